// Round 8
// baseline (22234.998 us; speedup 1.0000x reference)
//
#include <hip/hip_runtime.h>
#include <math.h>

// ============================================================================
// LARNN forward, MI355X — persistent kernel, 6 phases/step, fence-free sc1.
// ALL-F32 (bf16 diverges — chaotic recurrence, round 2). Deterministic BN.
// Round-8 changes: register ring-prefetch GEMM (A 4-slab / B 2-slab lookahead,
// one sync per slab), 4x4 microtile @256thr (FMA-bound 64x64x512 = ~6.8us),
// x-GEMMs precomputed one step ahead in idle slots, in-block BN for gates
// (h/out written directly, c in registers), symmetric flag barrier.
// ============================================================================

#define T_  128
#define B_  256
#define F_  128
#define H_  512
#define W_  16
#define H4_ 2048
#define EPS_ 1e-5f
#define BH_ (B_*H_)
#define NBLK 256
#define NTHR 256
#define FSTRIDE 32

typedef __attribute__((ext_vector_type(4))) float f4;
typedef unsigned long long u64;

__device__ __forceinline__ float eluf(float x){ return x > 0.f ? x : expf(x) - 1.f; }
__device__ __forceinline__ float sigf(float x){ return 1.f / (1.f + expf(-x)); }

// ---- LLC-coherent (sc1) relaxed accessors ----
__device__ __forceinline__ f4 ld_c(const float* p) {
  union { f4 v; u64 q[2]; } u;
  u.q[0] = __hip_atomic_load((const u64*)p,     __ATOMIC_RELAXED, __HIP_MEMORY_SCOPE_AGENT);
  u.q[1] = __hip_atomic_load((const u64*)p + 1, __ATOMIC_RELAXED, __HIP_MEMORY_SCOPE_AGENT);
  return u.v;
}
__device__ __forceinline__ void st_c(float* p, f4 v) {
  union { f4 v; u64 q[2]; } u; u.v = v;
  __hip_atomic_store((u64*)p,     u.q[0], __ATOMIC_RELAXED, __HIP_MEMORY_SCOPE_AGENT);
  __hip_atomic_store((u64*)p + 1, u.q[1], __ATOMIC_RELAXED, __HIP_MEMORY_SCOPE_AGENT);
}
__device__ __forceinline__ float ldf_c(const float* p) {
  unsigned u = __hip_atomic_load((const unsigned*)p, __ATOMIC_RELAXED, __HIP_MEMORY_SCOPE_AGENT);
  return __uint_as_float(u);
}
__device__ __forceinline__ void stf_c(float* p, float v) {
  __hip_atomic_store((unsigned*)p, __float_as_uint(v), __ATOMIC_RELAXED, __HIP_MEMORY_SCOPE_AGENT);
}

struct Params {
  const float *x, *W_ih, *b_ih, *W_hh, *Wq_in, *bq_in, *Wq, *bq, *Wk, *bk,
              *Wv, *bv, *Wo, *bo, *W_ac, *b_ac, *g_att, *be_att, *g_post, *be_post;
  float *out, *c, *h, *q, *Qh, *ctx, *attp, *preHF, *Kbuf, *Vbuf, *stA;
  float *preXb0, *preXb1, *qXb0, *qXb1;
  unsigned *arr;
};

// Symmetric flag barrier: thread i polls block i's flag. No RMW, no fences.
__device__ __forceinline__ void gbar(unsigned* arr, unsigned g) {
  asm volatile("s_waitcnt vmcnt(0) lgkmcnt(0)" ::: "memory");
  __syncthreads();
  if (threadIdx.x == 0)
    __hip_atomic_store(&arr[blockIdx.x * FSTRIDE], g, __ATOMIC_RELAXED, __HIP_MEMORY_SCOPE_AGENT);
  while (__hip_atomic_load(&arr[threadIdx.x * FSTRIDE], __ATOMIC_RELAXED, __HIP_MEMORY_SCOPE_AGENT) < g)
    __builtin_amdgcn_s_sleep(2);
  __syncthreads();
}

// ---------------------------------------------------------------------------
// 64x64 output tile, K = NS*32, 256 threads, 4x4 microtile.
// A: activations (sc1 or plain), ring-prefetched 4 slabs ahead.
// W: row-major [K][N], plain (L2-cached), prefetched 2 slabs ahead.
// LDS double-buffered; ONE __syncthreads per slab.
// ---------------------------------------------------------------------------
struct GP {
  const float* A; int lda; int a_sc1;
  const float* W;
  const float* b1; const float* b2;
  const float* addm;            // sc1, stride N
  int doElu; int doNorm;        // norm A on stage via scl/shf[k]
  float* out;                   // sc1, stride N
  float* stats; int mIdx;       // optional BN partials: stats[mIdx*1024 + {0,512}+n]
  int N; int m0; int n0;
};

template<int NS>
__device__ void gemm64(const GP& J, int tid,
                       float (*AsL)[32][72], float (*BsL)[32][72],
                       const float* scl, const float* shf) {
  const int arow = tid >> 2, akq = (tid & 3) * 8;
  const int bkk = tid >> 3, bn8 = (tid & 7) * 8;
  const int ty = tid >> 4, tx = tid & 15;

  const float* aBase = J.A + (size_t)(J.m0 + arow) * J.lda + akq;
  const float* wBase = J.W + (size_t)bkk * J.N + J.n0 + bn8;

  f4 ar[4][2]; f4 br[2][2];
  #pragma unroll
  for (int p = 0; p < 4; ++p) {
    if (p < NS) {
      const float* ap = aBase + p * 32;
      if (J.a_sc1) { ar[p][0] = ld_c(ap); ar[p][1] = ld_c(ap + 4); }
      else { ar[p][0] = *(const f4*)ap; ar[p][1] = *(const f4*)(ap + 4); }
    }
  }
  #pragma unroll
  for (int p = 0; p < 2; ++p) {
    if (p < NS) {
      const float* wp = wBase + (size_t)(p * 32) * J.N;
      br[p][0] = *(const f4*)wp; br[p][1] = *(const f4*)(wp + 4);
    }
  }
  f4 am[4];
  if (J.addm) {
    #pragma unroll
    for (int i = 0; i < 4; ++i)
      am[i] = ld_c(J.addm + (size_t)(J.m0 + ty * 4 + i) * J.N + J.n0 + tx * 4);
  }

  f4 acc[4] = {};

  #pragma unroll 1
  for (int so = 0; so < NS; so += 4) {
    #pragma unroll
    for (int si = 0; si < 4 && si < NS; ++si) {
      const int s = so + si;
      const int buf = si & 1;
      // stage A slab s (apply norm here if requested)
      #pragma unroll
      for (int h2 = 0; h2 < 2; ++h2) {
        f4 v = ar[si][h2];
        if (J.doNorm) {
          #pragma unroll
          for (int i = 0; i < 4; ++i) {
            int gk = s * 32 + akq + h2 * 4 + i;
            v[i] = v[i] * scl[gk] + shf[gk];
          }
        }
        #pragma unroll
        for (int i = 0; i < 4; ++i) AsL[buf][akq + h2 * 4 + i][arow] = v[i];
      }
      // issue A slab s+4 into the slot just consumed
      if (s + 4 < NS) {
        const float* ap = aBase + (s + 4) * 32;
        if (J.a_sc1) { ar[si][0] = ld_c(ap); ar[si][1] = ld_c(ap + 4); }
        else { ar[si][0] = *(const f4*)ap; ar[si][1] = *(const f4*)(ap + 4); }
      }
      // stage B slab s, issue B slab s+2
      *(f4*)&BsL[buf][bkk][bn8]     = br[si & 1][0];
      *(f4*)&BsL[buf][bkk][bn8 + 4] = br[si & 1][1];
      if (s + 2 < NS) {
        const float* wp = wBase + (size_t)((s + 2) * 32) * J.N;
        br[si & 1][0] = *(const f4*)wp; br[si & 1][1] = *(const f4*)(wp + 4);
      }
      __syncthreads();
      #pragma unroll 8
      for (int k = 0; k < 32; ++k) {
        f4 a = *(const f4*)&AsL[buf][k][ty * 4];
        f4 b = *(const f4*)&BsL[buf][k][tx * 4];
        #pragma unroll
        for (int i = 0; i < 4; ++i) {
          acc[i][0] = fmaf(a[i], b[0], acc[i][0]);
          acc[i][1] = fmaf(a[i], b[1], acc[i][1]);
          acc[i][2] = fmaf(a[i], b[2], acc[i][2]);
          acc[i][3] = fmaf(a[i], b[3], acc[i][3]);
        }
      }
    }
  }

  f4 bias = {0.f, 0.f, 0.f, 0.f};
  if (J.b1) bias += *(const f4*)(J.b1 + J.n0 + tx * 4);
  if (J.b2) bias += *(const f4*)(J.b2 + J.n0 + tx * 4);
  #pragma unroll
  for (int i = 0; i < 4; ++i) {
    f4 v = acc[i] + bias;
    if (J.addm) v += am[i];
    if (J.doElu) {
      #pragma unroll
      for (int j = 0; j < 4; ++j) v[j] = eluf(v[j]);
    }
    st_c(J.out + (size_t)(J.m0 + ty * 4 + i) * J.N + J.n0 + tx * 4, v);
    acc[i] = v;
  }

  if (J.stats) {   // deterministic per-64-row-tile column partials
    float* r1 = (float*)AsL;
    float* r2 = (float*)BsL;
    __syncthreads();
    f4 s4 = acc[0] + acc[1] + acc[2] + acc[3];
    f4 q4 = acc[0]*acc[0] + acc[1]*acc[1] + acc[2]*acc[2] + acc[3]*acc[3];
    *(f4*)&r1[ty * 64 + tx * 4] = s4;
    *(f4*)&r2[ty * 64 + tx * 4] = q4;
    __syncthreads();
    if (tid < 64) {
      float S = 0.f, Q = 0.f;
      #pragma unroll
      for (int y = 0; y < 16; ++y) { S += r1[y * 64 + tid]; Q += r2[y * 64 + tid]; }
      stf_c(J.stats + J.mIdx * 1024 + J.n0 + tid, S);
      stf_c(J.stats + J.mIdx * 1024 + 512 + J.n0 + tid, Q);
    }
  }
}

__global__ __launch_bounds__(NTHR, 1) void larnn(Params P) {
  __shared__ float AsL[2][32][72];
  __shared__ float BsL[2][32][72];
  __shared__ float scl[H_], shf[H_];
  __shared__ float Qs[H_];
  __shared__ float sc_[8][16], aw_[8][16];

  const int bid = blockIdx.x, tid = threadIdx.x;
  unsigned g = 0;

  f4 creg0 = {0.f,0.f,0.f,0.f}, creg1 = {0.f,0.f,0.f,0.f};   // gates blocks' c

  // ---------- phase 0: preX(0), qX(0) ----------
  if (bid < 128) {
    GP J{}; J.A = P.x; J.lda = F_; J.a_sc1 = 0; J.W = P.W_ih;
    J.b1 = P.b_ih; J.b2 = P.b_ac; J.out = P.preXb0; J.N = H4_;
    J.m0 = (bid >> 5) * 64; J.n0 = (bid & 31) * 64;
    gemm64<4>(J, tid, AsL, BsL, scl, shf);
  } else if (bid < 160) {
    int l = bid - 128;
    GP J{}; J.A = P.x; J.lda = F_; J.a_sc1 = 0; J.W = P.Wq_in;
    J.b1 = P.bq_in; J.out = P.qXb0; J.N = H_;
    J.m0 = (l >> 3) * 64; J.n0 = (l & 7) * 64;
    gemm64<4>(J, tid, AsL, BsL, scl, shf);
  }
  gbar(P.arr, ++g);

  for (int t = 0; t < T_; ++t) {
    const int slot = (t - 1) & 15;
    float* preX = (t & 1) ? P.preXb1 : P.preXb0;
    float* qX   = (t & 1) ? P.qXb1 : P.qXb0;
    float* preXn = (t & 1) ? P.preXb0 : P.preXb1;
    float* qXn   = (t & 1) ? P.qXb0 : P.qXb1;

    // ---------- PhA: q | K | V | preHF ----------
    if (bid < 32) {
      GP J{}; J.A = P.h; J.lda = H_; J.a_sc1 = 1;
      J.W = P.Wq_in + (size_t)F_ * H_; J.addm = qX; J.doElu = 1;
      J.out = P.q; J.N = H_;
      J.m0 = (bid >> 3) * 64; J.n0 = (bid & 7) * 64;
      gemm64<16>(J, tid, AsL, BsL, scl, shf);
    } else if (bid < 64) {
      int l = bid - 32;
      GP J{}; J.A = P.c; J.lda = H_; J.a_sc1 = 1;
      J.W = P.Wk; J.b1 = P.bk; J.doElu = 1;
      J.out = P.Kbuf + (size_t)slot * BH_; J.N = H_;
      J.m0 = (l >> 3) * 64; J.n0 = (l & 7) * 64;
      gemm64<16>(J, tid, AsL, BsL, scl, shf);
    } else if (bid < 96) {
      int l = bid - 64;
      GP J{}; J.A = P.c; J.lda = H_; J.a_sc1 = 1;
      J.W = P.Wv; J.b1 = P.bv; J.doElu = 1;
      J.out = P.Vbuf + (size_t)slot * BH_; J.N = H_;
      J.m0 = (l >> 3) * 64; J.n0 = (l & 7) * 64;
      gemm64<16>(J, tid, AsL, BsL, scl, shf);
    } else if (bid < 224) {
      int l = bid - 96;
      GP J{}; J.A = P.h; J.lda = H_; J.a_sc1 = 1;
      J.W = P.W_hh; J.addm = preX;
      J.out = P.preHF; J.N = H4_;
      J.m0 = (l >> 5) * 64; J.n0 = (l & 31) * 64;
      gemm64<16>(J, tid, AsL, BsL, scl, shf);
    }
    gbar(P.arr, ++g);

    // ---------- PhB: Qh | preX(t+1) | qX(t+1) ----------
    if (bid < 32) {
      GP J{}; J.A = P.q; J.lda = H_; J.a_sc1 = 1;
      J.W = P.Wq; J.b1 = P.bq;
      J.out = P.Qh; J.N = H_;
      J.m0 = (bid >> 3) * 64; J.n0 = (bid & 7) * 64;
      gemm64<16>(J, tid, AsL, BsL, scl, shf);
    } else if (bid < 160 && t + 1 < T_) {
      int l = bid - 32;
      GP J{}; J.A = P.x + (size_t)(t + 1) * B_ * F_; J.lda = F_; J.a_sc1 = 0;
      J.W = P.W_ih; J.b1 = P.b_ih; J.b2 = P.b_ac;
      J.out = preXn; J.N = H4_;
      J.m0 = (l >> 5) * 64; J.n0 = (l & 31) * 64;
      gemm64<4>(J, tid, AsL, BsL, scl, shf);
    } else if (bid < 192 && t + 1 < T_) {
      int l = bid - 160;
      GP J{}; J.A = P.x + (size_t)(t + 1) * B_ * F_; J.lda = F_; J.a_sc1 = 0;
      J.W = P.Wq_in; J.b1 = P.bq_in;
      J.out = qXn; J.N = H_;
      J.m0 = (l >> 3) * 64; J.n0 = (l & 7) * 64;
      gemm64<4>(J, tid, AsL, BsL, scl, shf);
    }
    gbar(P.arr, ++g);

    // ---------- PhC: attention (block = batch row) ----------
    {
      const int b = bid;
      const int nv = (t + 1 < W_) ? t + 1 : W_;
      if (tid < 128) *(f4*)&Qs[tid * 4] = ld_c(P.Qh + (size_t)b * H_ + tid * 4);
      __syncthreads();
      {
        const int u = tid >> 1, half = tid & 1;
        const int hh = u >> 4, w = u & 15;
        if (w < nv) {
          const int sl = (t - 1 - w) & 15;
          const float* kp = P.Kbuf + ((size_t)sl * B_ + b) * H_ + hh * 64 + half * 32;
          const float* qp = Qs + hh * 64 + half * 32;
          float s = 0.f;
          #pragma unroll
          for (int j = 0; j < 8; ++j) {
            f4 kv = ld_c(kp + j * 4);
            f4 qv = *(const f4*)(qp + j * 4);
            s = fmaf(kv[0], qv[0], fmaf(kv[1], qv[1], fmaf(kv[2], qv[2], fmaf(kv[3], qv[3], s))));
          }
          s += __shfl_xor(s, 1);
          if (half == 0) sc_[hh][w] = s * 0.125f;
        }
      }
      __syncthreads();
      if (tid < 8) {
        float mx = -1e30f;
        for (int w = 0; w < nv; ++w) mx = fmaxf(mx, sc_[tid][w]);
        float ss = 0.f;
        for (int w = 0; w < nv; ++w) { float e = expf(sc_[tid][w] - mx); aw_[tid][w] = e; ss += e; }
        float inv = 1.f / ss;
        for (int w = 0; w < nv; ++w) aw_[tid][w] *= inv;
      }
      __syncthreads();
      {
        const int cg = tid >> 1, wh = tid & 1;
        const int hh = cg >> 4;
        f4 o = {0.f, 0.f, 0.f, 0.f};
        #pragma unroll
        for (int j = 0; j < 8; ++j) {
          int w = wh * 8 + j;
          if (w < nv) {
            const int sl = (t - 1 - w) & 15;
            f4 vv = ld_c(P.Vbuf + ((size_t)sl * B_ + b) * H_ + cg * 4);
            float a_ = aw_[hh][w];
            o[0] = fmaf(a_, vv[0], o[0]); o[1] = fmaf(a_, vv[1], o[1]);
            o[2] = fmaf(a_, vv[2], o[2]); o[3] = fmaf(a_, vv[3], o[3]);
          }
        }
        #pragma unroll
        for (int i = 0; i < 4; ++i) o[i] += __shfl_xor(o[i], 1);
        if (wh == 0) st_c(P.ctx + (size_t)b * H_ + cg * 4, o);
      }
    }
    gbar(P.arr, ++g);

    // ---------- PhD: attp = elu(ctx@Wo + bo) + BN partials ----------
    if (bid < 32) {
      GP J{}; J.A = P.ctx; J.lda = H_; J.a_sc1 = 1;
      J.W = P.Wo; J.b1 = P.bo; J.doElu = 1;
      J.out = P.attp; J.stats = P.stA; J.N = H_;
      J.m0 = (bid >> 3) * 64; J.n0 = (bid & 7) * 64; J.mIdx = J.m0 >> 6;
      gemm64<16>(J, tid, AsL, BsL, scl, shf);
    }
    gbar(P.arr, ++g);

    // ---------- PhE: preHF += BN(attp) @ W_ac ----------
    if (bid < 128) {
      for (int cc = tid; cc < H_; cc += NTHR) {
        float S = ldf_c(P.stA + cc) + ldf_c(P.stA + 1024 + cc)
                + ldf_c(P.stA + 2048 + cc) + ldf_c(P.stA + 3072 + cc);
        float Q = ldf_c(P.stA + 512 + cc) + ldf_c(P.stA + 1536 + cc)
                + ldf_c(P.stA + 2560 + cc) + ldf_c(P.stA + 3584 + cc);
        float mu = S * (1.f / B_), var = Q * (1.f / B_) - mu * mu;
        float sc = rsqrtf(var + EPS_) * P.g_att[cc];
        scl[cc] = sc; shf[cc] = P.be_att[cc] - mu * sc;
      }
      __syncthreads();
      GP J{}; J.A = P.attp; J.lda = H_; J.a_sc1 = 1; J.doNorm = 1;
      J.W = P.W_ac; J.addm = P.preHF;
      J.out = P.preHF; J.N = H4_;
      J.m0 = (bid >> 5) * 64; J.n0 = (bid & 31) * 64;
      gemm64<16>(J, tid, AsL, BsL, scl, shf);
    }
    gbar(P.arr, ++g);

    // ---------- PhF: gates + in-block BN -> c, h, out[t] ----------
    if (bid < 64) {
      const int gc = bid * 8;
      const int r = tid;
      const float* pb = P.preHF + (size_t)r * H4_ + gc;
      f4 pA0 = ld_c(pb),        pA1 = ld_c(pb + 4);
      f4 pF0 = ld_c(pb + 512),  pF1 = ld_c(pb + 516);
      f4 pI0 = ld_c(pb + 1024), pI1 = ld_c(pb + 1028);
      f4 pO0 = ld_c(pb + 1536), pO1 = ld_c(pb + 1540);
      f4 cn0, cn1, hv0, hv1;
      #pragma unroll
      for (int i = 0; i < 4; ++i) {
        float iv = tanhf(pA0[i]);
        float fg = sigf(pF0[i]), ig = sigf(pI0[i]), og = sigf(pO0[i]);
        cn0[i] = iv * ig + creg0[i] * fg;
        hv0[i] = og * eluf(cn0[i]);
        float iv1 = tanhf(pA1[i]);
        float fg1 = sigf(pF1[i]), ig1 = sigf(pI1[i]), og1 = sigf(pO1[i]);
        cn1[i] = iv1 * ig1 + creg1[i] * fg1;
        hv1[i] = og1 * eluf(cn1[i]);
      }
      creg0 = cn0; creg1 = cn1;
      st_c(P.c + (size_t)r * H_ + gc, cn0);
      st_c(P.c + (size_t)r * H_ + gc + 4, cn1);
      float* r1 = (float*)AsL;   // [256][8]
      float* r2 = (float*)BsL;
      *(f4*)&r1[r * 8]     = hv0; *(f4*)&r1[r * 8 + 4] = hv1;
      *(f4*)&r2[r * 8]     = hv0 * hv0; *(f4*)&r2[r * 8 + 4] = hv1 * hv1;
      __syncthreads();
      for (int off = 128; off >= 1; off >>= 1) {
        if (r < off) {
          *(f4*)&r1[r * 8]     += *(f4*)&r1[(r + off) * 8];
          *(f4*)&r1[r * 8 + 4] += *(f4*)&r1[(r + off) * 8 + 4];
          *(f4*)&r2[r * 8]     += *(f4*)&r2[(r + off) * 8];
          *(f4*)&r2[r * 8 + 4] += *(f4*)&r2[(r + off) * 8 + 4];
        }
        __syncthreads();
      }
      if (tid < 8) {
        float S = r1[tid], Q = r2[tid];
        float mu = S * (1.f / B_), var = Q * (1.f / B_) - mu * mu;
        float sc = rsqrtf(var + EPS_) * P.g_post[gc + tid];
        scl[tid] = sc; shf[tid] = P.be_post[gc + tid] - mu * sc;
      }
      __syncthreads();
      f4 hn0, hn1;
      #pragma unroll
      for (int i = 0; i < 4; ++i) {
        hn0[i] = hv0[i] * scl[i] + shf[i];
        hn1[i] = hv1[i] * scl[i + 4] + shf[i + 4];
      }
      st_c(P.h + (size_t)r * H_ + gc, hn0);
      st_c(P.h + (size_t)r * H_ + gc + 4, hn1);
      *(f4*)&P.out[(size_t)t * BH_ + (size_t)r * H_ + gc] = hn0;
      *(f4*)&P.out[(size_t)t * BH_ + (size_t)r * H_ + gc + 4] = hn1;
    }
    gbar(P.arr, ++g);
  }
}

#define SYNC_UINTS (NBLK * FSTRIDE)

__global__ __launch_bounds__(256) void pinit(float* c, float* h, unsigned* sync) {
  const int i = blockIdx.x * 256 + threadIdx.x;
  if (i < BH_) { c[i] = 0.f; h[i] = 0.f; }
  if (i < SYNC_UINTS) sync[i] = 0u;
}

extern "C" void kernel_launch(void* const* d_in, const int* in_sizes, int n_in,
                              void* d_out, int out_size, void* d_ws, size_t ws_size,
                              hipStream_t stream) {
  Params P;
  P.x      = (const float*)d_in[0];
  P.W_ih   = (const float*)d_in[1];
  P.b_ih   = (const float*)d_in[2];
  P.W_hh   = (const float*)d_in[3];
  P.Wq_in  = (const float*)d_in[4];
  P.bq_in  = (const float*)d_in[5];
  P.Wq     = (const float*)d_in[6];
  P.bq     = (const float*)d_in[7];
  P.Wk     = (const float*)d_in[8];
  P.bk     = (const float*)d_in[9];
  P.Wv     = (const float*)d_in[10];
  P.bv     = (const float*)d_in[11];
  P.Wo     = (const float*)d_in[12];
  P.bo     = (const float*)d_in[13];
  P.W_ac   = (const float*)d_in[14];
  P.b_ac   = (const float*)d_in[15];
  P.g_att  = (const float*)d_in[16];
  P.be_att = (const float*)d_in[17];
  P.g_post = (const float*)d_in[18];
  P.be_post= (const float*)d_in[19];
  P.out    = (float*)d_out;

  unsigned* sync = (unsigned*)d_ws;
  P.arr = sync;
  float* fb = (float*)d_ws + SYNC_UINTS;
  P.c     = fb; fb += BH_;
  P.h     = fb; fb += BH_;
  P.q     = fb; fb += BH_;
  P.Qh    = fb; fb += BH_;
  P.ctx   = fb; fb += BH_;
  P.attp  = fb; fb += BH_;
  P.preHF = fb; fb += (size_t)B_ * H4_;
  P.Kbuf  = fb; fb += (size_t)W_ * BH_;
  P.Vbuf  = fb; fb += (size_t)W_ * BH_;
  P.preXb0= fb; fb += (size_t)B_ * H4_;
  P.preXb1= fb; fb += (size_t)B_ * H4_;
  P.qXb0  = fb; fb += BH_;
  P.qXb1  = fb; fb += BH_;
  P.stA   = fb; fb += 4096;

  pinit<<<(BH_ + 255) / 256, 256, 0, stream>>>(P.c, P.h, sync);
  larnn<<<NBLK, NTHR, 0, stream>>>(P);
}